// Round 2
// baseline (124.329 us; speedup 1.0000x reference)
//
#include <hip/hip_runtime.h>

constexpr int B = 32;
constexpr int T = 128;
constexpr int N = 4096;
constexpr int UNR = 8;
constexpr int NG = T / UNR;   // 16 groups

__global__ __launch_bounds__(256) void lif_scan_kernel(
    const float* __restrict__ x,
    const float* __restrict__ tau_mem,
    const float* __restrict__ v_th,
    float* __restrict__ out)
{
    const int tid = blockIdx.x * blockDim.x + threadIdx.x;   // 0 .. B*N-1
    const int b   = tid >> 12;          // / N
    const int n   = tid & (N - 1);      // % N

    // per-neuron params: clip in fp32 exactly like the reference, then promote
    const float tmf = fminf(fmaxf(tau_mem[n], 0.8f), 0.98f);
    const float thf = fminf(fmaxf(v_th[n],  0.05f), 0.5f);

    const double tm = (double)tmf;
    const double cm = 1.0 - tm;
    const double th = (double)thf;

    const size_t base = (size_t)b * T * N + (size_t)n;
    const float* xp = x + base;
    float*       op = out + base;

    double is = 0.0, v = 0.0;

    float buf[UNR];
#pragma unroll
    for (int u = 0; u < UNR; ++u)
        buf[u] = __builtin_nontemporal_load(xp + (size_t)u * N);

    for (int g = 0; g < NG; ++g) {
        float nbuf[UNR];
        if (g + 1 < NG) {
            const float* xg = xp + (size_t)(g + 1) * UNR * N;
#pragma unroll
            for (int u = 0; u < UNR; ++u)
                nbuf[u] = __builtin_nontemporal_load(xg + (size_t)u * N);
        }

        float* og = op + (size_t)g * UNR * N;
#pragma unroll
        for (int u = 0; u < UNR; ++u) {
            // i_syn[t] = 0.5 * i_syn[t-1] + x[t]
            is = fma(0.5, is, (double)buf[u]);
            // v[t] = tau * v[t-1] + (1 - tau) * i_syn[t]
            v = fma(tm, v, cm * is);
            __builtin_nontemporal_store((v >= th) ? 1.0f : 0.0f,
                                        og + (size_t)u * N);
        }

#pragma unroll
        for (int u = 0; u < UNR; ++u) buf[u] = nbuf[u];
    }
}

extern "C" void kernel_launch(void* const* d_in, const int* in_sizes, int n_in,
                              void* d_out, int out_size, void* d_ws, size_t ws_size,
                              hipStream_t stream) {
    const float* x       = (const float*)d_in[0];
    const float* tau_mem = (const float*)d_in[1];
    const float* v_th    = (const float*)d_in[2];
    float* out           = (float*)d_out;

    const int threads = B * N;                // 131072
    dim3 block(256);
    dim3 grid(threads / 256);                 // 512 blocks -> 2 per CU, 8 waves/CU
    lif_scan_kernel<<<grid, block, 0, stream>>>(x, tau_mem, v_th, out);
}

// Round 6
// 111.506 us; speedup vs baseline: 1.1150x; 1.1150x over previous
//
#include <hip/hip_runtime.h>

constexpr int B = 32;
constexpr int T = 128;
constexpr int N = 4096;
constexpr int UNR = 16;          // time-steps per pipeline group
constexpr int NG  = T / UNR;     // 8 groups

typedef float f32x2 __attribute__((ext_vector_type(2)));

__global__ __launch_bounds__(256) void lif_scan_kernel(
    const float* __restrict__ x,
    const float* __restrict__ tau_mem,
    const float* __restrict__ v_th,
    float* __restrict__ out)
{
    const int tid = blockIdx.x * blockDim.x + threadIdx.x;   // 0 .. B*N/2-1
    const int b   = tid >> 11;               // / (N/2)
    const int n2  = (tid & 2047) * 2;        // neuron pair index

    // per-neuron params: clip in fp32 exactly like the reference, then promote
    const f32x2 tm = *reinterpret_cast<const f32x2*>(tau_mem + n2);
    const f32x2 tv = *reinterpret_cast<const f32x2*>(v_th + n2);

    const double t0 = (double)fminf(fmaxf(tm.x, 0.8f), 0.98f);
    const double t1 = (double)fminf(fmaxf(tm.y, 0.8f), 0.98f);
    const double c0 = 1.0 - t0, c1 = 1.0 - t1;
    const double h0 = (double)fminf(fmaxf(tv.x, 0.05f), 0.5f);
    const double h1 = (double)fminf(fmaxf(tv.y, 0.05f), 0.5f);

    const size_t base = (size_t)b * T * N + (size_t)n2;
    const float* xp = x + base;
    float*       op = out + base;

    double is0 = 0.0, is1 = 0.0, v0 = 0.0, v1 = 0.0;

    f32x2 buf[UNR];
#pragma unroll
    for (int u = 0; u < UNR; ++u)
        buf[u] = *reinterpret_cast<const f32x2*>(xp + (size_t)u * N);

    for (int g = 0; g < NG; ++g) {
        f32x2 nbuf[UNR];
        if (g + 1 < NG) {
            const float* xg = xp + (size_t)(g + 1) * UNR * N;
#pragma unroll
            for (int u = 0; u < UNR; ++u)
                nbuf[u] = *reinterpret_cast<const f32x2*>(xg + (size_t)u * N);
        }

        float* og = op + (size_t)g * UNR * N;
#pragma unroll
        for (int u = 0; u < UNR; ++u) {
            // i_syn[t] = 0.5 * i_syn[t-1] + x[t]
            is0 = fma(0.5, is0, (double)buf[u].x);
            is1 = fma(0.5, is1, (double)buf[u].y);
            // v[t] = tau * v[t-1] + (1 - tau) * i_syn[t]
            v0 = fma(t0, v0, c0 * is0);
            v1 = fma(t1, v1, c1 * is1);
            f32x2 s;
            s.x = (v0 >= h0) ? 1.0f : 0.0f;
            s.y = (v1 >= h1) ? 1.0f : 0.0f;
            __builtin_nontemporal_store(s, reinterpret_cast<f32x2*>(og + (size_t)u * N));
        }

#pragma unroll
        for (int u = 0; u < UNR; ++u) buf[u] = nbuf[u];
    }
}

extern "C" void kernel_launch(void* const* d_in, const int* in_sizes, int n_in,
                              void* d_out, int out_size, void* d_ws, size_t ws_size,
                              hipStream_t stream) {
    const float* x       = (const float*)d_in[0];
    const float* tau_mem = (const float*)d_in[1];
    const float* v_th    = (const float*)d_in[2];
    float* out           = (float*)d_out;

    const int threads = B * (N / 2);          // 65536
    dim3 block(256);
    dim3 grid(threads / 256);                 // 256 blocks
    lif_scan_kernel<<<grid, block, 0, stream>>>(x, tau_mem, v_th, out);
}